// Round 2
// baseline (74.138 us; speedup 1.0000x reference)
//
#include <hip/hip_runtime.h>
#include <hip/hip_bf16.h>

#define B_ 32
#define L_ 2048
#define E_ 256
#define H_ 256
#define MAXSTEP 20

typedef __attribute__((ext_vector_type(4))) float f32x4;
typedef __attribute__((ext_vector_type(8))) short bf16x8;
using bf16 = __hip_bfloat16;

__device__ inline short cvt1(float x) {
    bf16 b = __float2bfloat16(x);
    return *reinterpret_cast<short*>(&b);
}

// Transpose + convert: cnn fp32 [s][e][h] -> wt bf16 [s][h][e] (K-contiguous B operand).
__global__ void transpose_w_kernel(const float* __restrict__ cnn, short* __restrict__ wt) {
    __shared__ short tile[32][33];  // +1 pad breaks bank conflicts on transposed read
    const int s  = blockIdx.z;
    const int e0 = blockIdx.y * 32;
    const int h0 = blockIdx.x * 32;
    const int tx = threadIdx.x;     // 0..31
    const int ty = threadIdx.y;     // 0..7
    const float* src = cnn + ((size_t)s * E_ + e0) * H_ + h0;
#pragma unroll
    for (int i = ty; i < 32; i += 8)
        tile[i][tx] = cvt1(src[(size_t)i * H_ + tx]);
    __syncthreads();
    short* dst = wt + ((size_t)s * H_ + h0) * E_ + e0;
#pragma unroll
    for (int i = ty; i < 32; i += 8)
        dst[(size_t)i * E_ + tx] = tile[tx][i];
}

// One block per position l. 4 waves; wave w computes rows b=0..31, cols h in [w*64, w*64+64).
// mfma_f32_16x16x32_bf16: A row = lane&15, k = (lane>>4)*8+j (contiguous 8);
//                         B col = lane&15, same k mapping;
//                         C/D col = lane&15, row = (lane>>4)*4 + reg.
template <bool TRANS>
__global__ __launch_bounds__(256, 4) void vaw_mfma_kernel(
        const float* __restrict__ A, const void* __restrict__ W, float* __restrict__ out) {
    const int l    = blockIdx.x;
    const int s    = l % MAXSTEP;
    const int wv   = threadIdx.x >> 6;
    const int lane = threadIdx.x & 63;
    const int r    = lane & 15;
    const int g    = lane >> 4;
    const int nbase = wv * 64;

    f32x4 acc[2][4] = {};

    const float* aptr0 = A + ((size_t)r * L_ + l) * E_ + g * 8;
    const float* aptr1 = A + ((size_t)(r + 16) * L_ + l) * E_ + g * 8;

#pragma unroll 2
    for (int k0 = 0; k0 < E_; k0 += 32) {
        f32x4 a0lo = *(const f32x4*)(aptr0 + k0);
        f32x4 a0hi = *(const f32x4*)(aptr0 + k0 + 4);
        f32x4 a1lo = *(const f32x4*)(aptr1 + k0);
        f32x4 a1hi = *(const f32x4*)(aptr1 + k0 + 4);
        bf16x8 a0, a1;
#pragma unroll
        for (int j = 0; j < 4; ++j) {
            a0[j]     = cvt1(a0lo[j]);
            a0[j + 4] = cvt1(a0hi[j]);
            a1[j]     = cvt1(a1lo[j]);
            a1[j + 4] = cvt1(a1hi[j]);
        }
        bf16x8 b0, b1, b2, b3;
        if constexpr (TRANS) {
            const short* wt = (const short*)W + ((size_t)s * H_ + nbase + r) * E_ + g * 8;
            b0 = *(const bf16x8*)(wt + (size_t)0 * 16 * E_ + k0);
            b1 = *(const bf16x8*)(wt + (size_t)1 * 16 * E_ + k0);
            b2 = *(const bf16x8*)(wt + (size_t)2 * 16 * E_ + k0);
            b3 = *(const bf16x8*)(wt + (size_t)3 * 16 * E_ + k0);
        } else {
            const float* Wf = (const float*)W + (size_t)s * E_ * H_;
#pragma unroll
            for (int j = 0; j < 8; ++j) {
                const size_t krow = (size_t)(k0 + g * 8 + j) * H_;
                b0[j] = cvt1(Wf[krow + nbase +  0 + r]);
                b1[j] = cvt1(Wf[krow + nbase + 16 + r]);
                b2[j] = cvt1(Wf[krow + nbase + 32 + r]);
                b3[j] = cvt1(Wf[krow + nbase + 48 + r]);
            }
        }
        acc[0][0] = __builtin_amdgcn_mfma_f32_16x16x32_bf16(a0, b0, acc[0][0], 0, 0, 0);
        acc[0][1] = __builtin_amdgcn_mfma_f32_16x16x32_bf16(a0, b1, acc[0][1], 0, 0, 0);
        acc[0][2] = __builtin_amdgcn_mfma_f32_16x16x32_bf16(a0, b2, acc[0][2], 0, 0, 0);
        acc[0][3] = __builtin_amdgcn_mfma_f32_16x16x32_bf16(a0, b3, acc[0][3], 0, 0, 0);
        acc[1][0] = __builtin_amdgcn_mfma_f32_16x16x32_bf16(a1, b0, acc[1][0], 0, 0, 0);
        acc[1][1] = __builtin_amdgcn_mfma_f32_16x16x32_bf16(a1, b1, acc[1][1], 0, 0, 0);
        acc[1][2] = __builtin_amdgcn_mfma_f32_16x16x32_bf16(a1, b2, acc[1][2], 0, 0, 0);
        acc[1][3] = __builtin_amdgcn_mfma_f32_16x16x32_bf16(a1, b3, acc[1][3], 0, 0, 0);
    }

    const int row0 = g * 4;
#pragma unroll
    for (int mf = 0; mf < 2; ++mf) {
#pragma unroll
        for (int nf = 0; nf < 4; ++nf) {
            const int h = nbase + nf * 16 + r;
#pragma unroll
            for (int i = 0; i < 4; ++i) {
                const int bb = mf * 16 + row0 + i;
                out[((size_t)bb * L_ + l) * H_ + h] = acc[mf][nf][i];
            }
        }
    }
    if (l == L_ - 1) {
        float* out2 = out + (size_t)B_ * L_ * H_;
#pragma unroll
        for (int mf = 0; mf < 2; ++mf)
#pragma unroll
            for (int nf = 0; nf < 4; ++nf) {
                const int h = nbase + nf * 16 + r;
#pragma unroll
                for (int i = 0; i < 4; ++i) {
                    const int bb = mf * 16 + row0 + i;
                    out2[(size_t)bb * H_ + h] = acc[mf][nf][i];
                }
            }
    }
}

extern "C" void kernel_launch(void* const* d_in, const int* in_sizes, int n_in,
                              void* d_out, int out_size, void* d_ws, size_t ws_size,
                              hipStream_t stream) {
    const float* word_rep = (const float*)d_in[0];
    const float* cnn      = (const float*)d_in[1];
    float* out = (float*)d_out;

    const size_t wt_bytes = (size_t)MAXSTEP * E_ * H_ * sizeof(short);
    if (ws_size >= wt_bytes) {
        short* wt = (short*)d_ws;
        transpose_w_kernel<<<dim3(8, 8, 20), dim3(32, 8), 0, stream>>>(cnn, wt);
        vaw_mfma_kernel<true><<<dim3(L_), dim3(256), 0, stream>>>(word_rep, wt, out);
    } else {
        vaw_mfma_kernel<false><<<dim3(L_), dim3(256), 0, stream>>>(word_rep, cnn, out);
    }
}